// Round 2
// baseline (691.707 us; speedup 1.0000x reference)
//
#include <hip/hip_runtime.h>

#define BB   16
#define CC   32
#define HH   384
#define WW   384
#define HW   (HH * WW)        // 147456
#define HID  128
#define KOUT 288              // NK*K*K = 32*9
#define BAND 16               // rows per conv block
#define TW   (WW + 2)         // LDS tile width (386)

// ---------------------------------------------------------------------------
// 1) Global average pool: one block per (b,c) plane. float4 loads.
// ---------------------------------------------------------------------------
__global__ __launch_bounds__(256) void pool_kernel(const float* __restrict__ x,
                                                   float* __restrict__ pooled) {
    const int bc = blockIdx.x;
    const float4* pv = (const float4*)(x + (size_t)bc * HW);
    float s = 0.f;
    for (int i = threadIdx.x; i < HW / 4; i += 256) {
        float4 v = pv[i];
        s += v.x + v.y + v.z + v.w;
    }
#pragma unroll
    for (int off = 32; off; off >>= 1) s += __shfl_down(s, off);
    __shared__ float red[4];
    if ((threadIdx.x & 63) == 0) red[threadIdx.x >> 6] = s;
    __syncthreads();
    if (threadIdx.x == 0) {
        float t = red[0] + red[1] + red[2] + red[3];
        pooled[bc] = t * (1.0f / (float)HW);
    }
}

// ---------------------------------------------------------------------------
// 2) MLP kernel generator: one block per batch sample. fp32.
//    hdn[j] = relu(b1[j] + sum_c pooled[c]*w1[c,j])          (j in [0,128))
//    kern[o] = b2[o] + sum_j hdn[j]*w2[j,o]                  (o in [0,288))
// ---------------------------------------------------------------------------
__global__ __launch_bounds__(128) void mlp_kernel(const float* __restrict__ pooled,
                                                  const float* __restrict__ w1,
                                                  const float* __restrict__ b1,
                                                  const float* __restrict__ w2,
                                                  const float* __restrict__ b2,
                                                  float* __restrict__ kern) {
    const int b   = blockIdx.x;
    const int tid = threadIdx.x;
    __shared__ float pc[CC];
    __shared__ float hdn[HID];
    if (tid < CC) pc[tid] = pooled[b * CC + tid];
    __syncthreads();

    float a = b1[tid];
#pragma unroll
    for (int c = 0; c < CC; ++c) a += pc[c] * w1[c * HID + tid];
    hdn[tid] = fmaxf(a, 0.f);
    __syncthreads();

    for (int o = tid; o < KOUT; o += 128) {
        float a2 = b2[o];
#pragma unroll 8
        for (int j = 0; j < HID; ++j) a2 += hdn[j] * w2[j * KOUT + o];
        kern[b * KOUT + o] = a2;
    }
}

// ---------------------------------------------------------------------------
// 3) Depthwise 3x3 conv, zero padding. One block per (plane, 16-row band).
//    LDS tile (BAND+2) x (WW+2) fp32 with zero halo; 24 pixels/thread.
//    NK == C == 32: plane bc uses kernel weights kern[bc*9 .. bc*9+8].
// ---------------------------------------------------------------------------
__global__ __launch_bounds__(256) void conv_kernel(const float* __restrict__ x,
                                                   const float* __restrict__ kern,
                                                   float* __restrict__ out) {
    const int nbands = HH / BAND;               // 24
    const int band = blockIdx.x % nbands;
    const int bc   = blockIdx.x / nbands;
    const float* xp = x + (size_t)bc * HW;

    __shared__ float tile[(BAND + 2) * TW];

    const int row0 = band * BAND - 1;
    for (int l = threadIdx.x; l < (BAND + 2) * TW; l += 256) {
        int r  = l / TW;
        int cc = l - r * TW;
        int gr = row0 + r;
        int gc = cc - 1;
        float v = 0.f;
        if ((unsigned)gr < HH && (unsigned)gc < WW) v = xp[gr * WW + gc];
        tile[l] = v;
    }

    float w[9];
    const float* kw = kern + (size_t)bc * 9;
#pragma unroll
    for (int t = 0; t < 9; ++t) w[t] = kw[t];
    __syncthreads();

    float* op = out + (size_t)bc * HW + band * BAND * WW;
    for (int p = threadIdx.x; p < BAND * WW; p += 256) {
        int r = p / WW;
        int c = p - r * WW;
        const float* t0 = &tile[r * TW + c];
        float acc = w[0] * t0[0]          + w[1] * t0[1]          + w[2] * t0[2]
                  + w[3] * t0[TW]         + w[4] * t0[TW + 1]     + w[5] * t0[TW + 2]
                  + w[6] * t0[2 * TW]     + w[7] * t0[2 * TW + 1] + w[8] * t0[2 * TW + 2];
        op[p] = acc;
    }
}

// ---------------------------------------------------------------------------
extern "C" void kernel_launch(void* const* d_in, const int* in_sizes, int n_in,
                              void* d_out, int out_size, void* d_ws, size_t ws_size,
                              hipStream_t stream) {
    const float* x  = (const float*)d_in[0];
    const float* w1 = (const float*)d_in[1];
    const float* b1 = (const float*)d_in[2];
    const float* w2 = (const float*)d_in[3];
    const float* b2 = (const float*)d_in[4];
    float* out = (float*)d_out;

    float* pooled = (float*)d_ws;        // 512 floats
    float* kern   = pooled + BB * CC;    // 16*288 = 4608 floats

    pool_kernel<<<BB * CC, 256, 0, stream>>>(x, pooled);
    mlp_kernel<<<BB, 128, 0, stream>>>(pooled, w1, b1, w2, b2, kern);
    conv_kernel<<<BB * CC * (HH / BAND), 256, 0, stream>>>(x, kern, out);
}